// Round 9
// baseline (285.302 us; speedup 1.0000x reference)
//
#include <hip/hip_runtime.h>

// EquivariantLinear: out[pos, c, m] = pw * sum_k x[pos, k, m] * W_{l(m)}[k, c]
// pos = 32768, C_IN = C_OUT = 256, FEAT = 9 (irreps 1,3,5), pw = 1/16.
// R11: persistent-2 blocks/CU, single 76KB buffer, LOAD-EARLY pipelining.
//  - 512 blocks x 512 thr, each runs NT=4 tiles (POSB=16). LDS = 76032 B
//    -> 2 blocks/CU (the only regime that ever won: R2/R7/R8).
//  - Per tile: compute -> bar -> outstage ct0 -> scatter ct1 (acc now DEAD)
//    -> ISSUE next tile's 24 loads (regs reuse acc slots; peak stays ~128)
//    -> read+nt-store ct1 -> bar -> cvt+ds_write next tile -> bar.
//    Loads fill during ~half the outstage + all of stage-write span ->
//    HBM read duty extends beyond the stage phase (R8: reads only in stage).
//  - All in-loop barriers are raw s_barrier + lgkmcnt(0) ONLY: nt stores are
//    never drained (R3's failure mechanism avoided). Worst case the compiler
//    emits vmcnt(0) at stage-write: one nt-store-ack wait per tile, bounded.
//  - launch_bounds(512,4) pins 4 waves/SIMD (16/CU) = the R8 regime.
//  - Phases themselves identical to R8 (36-B-unit loads, cvt_pk, b16 LDS
//    scatter-stage, 2-pass MFMA, per-wave LDS out-stage, nt stores).

typedef float f32x4 __attribute__((ext_vector_type(4)));
typedef float f32x4u __attribute__((ext_vector_type(4), aligned(4)));
typedef short s16x8 __attribute__((ext_vector_type(8)));

#define POSB 16                      // positions per tile
#define XS_KS 264                    // padded k-stride (elems)
#define XS_MS (POSB * XS_KS)         // 4224 elems per m-plane
#define SMEM_BYTES (9 * XS_MS * 2)   // 76032 B (single buffer)
#define STG_ROW 148                  // out-stage row stride (floats); 144 used
#define NT 4                         // tiles per block; 512 x 4 = 2048 tiles
#define TILE_FLOATS (POSB * 2304)    // 36864

__device__ __forceinline__ unsigned short f2bf(float f) {
  unsigned u = __float_as_uint(f);
  return (unsigned short)((u + 0x7FFFu + ((u >> 16) & 1u)) >> 16);
}

__device__ __forceinline__ unsigned cvt_pk_bf16(float lo, float hi) {
  unsigned r;
  asm("v_cvt_pk_bf16_f32 %0, %1, %2" : "=v"(r) : "v"(lo), "v"(hi));
  return r;
}

// raw barrier: LDS ordering only, no vmcnt drain (stores stay in flight)
__device__ __forceinline__ void bar_nodrain() {
  asm volatile("s_waitcnt lgkmcnt(0)\n\ts_barrier" ::: "memory");
}

// ---- prep: W^T bf16 image in ws: wt[irr][c][k] = pw * w_irr[k][c] ----
__global__ void prep_w(const float* __restrict__ w0, const float* __restrict__ w1,
                       const float* __restrict__ w2, unsigned short* __restrict__ wt) {
  const int b = blockIdx.x;
  const int irr = b / 16;
  const int tile = b % 16;
  const int k0 = (tile >> 2) << 6;
  const int c0 = (tile & 3) << 6;
  const float* w = (irr == 0) ? w0 : ((irr == 1) ? w1 : w2);
  __shared__ float lt[64 * 65];
  const int t = threadIdx.x;
#pragma unroll
  for (int i = 0; i < 16; ++i) {
    int e = t + (i << 8);
    int kk = e >> 6, cc = e & 63;
    lt[cc * 65 + kk] = w[(k0 + kk) * 256 + (c0 + cc)];
  }
  __syncthreads();
#pragma unroll
  for (int i = 0; i < 16; ++i) {
    int e = t + (i << 8);
    int cc = e >> 6, kk = e & 63;
    wt[irr * 65536 + (c0 + cc) * 256 + (k0 + kk)] = f2bf(lt[cc * 65 + kk] * 0.0625f);
  }
}

// issue the 24 global loads of one tile's 8 thread-units (36-B units)
__device__ __forceinline__ void load8(const float* __restrict__ xb, int t,
                                      f32x4u* va, f32x4u* vb, float* vc) {
#pragma unroll
  for (int i = 0; i < 8; ++i) {
    const float* s = xb + (t + (i << 9)) * 9;
    va[i] = *reinterpret_cast<const f32x4u*>(s);
    vb[i] = *reinterpret_cast<const f32x4u*>(s + 4);
    vc[i] = s[8];
  }
}

// convert + scatter 8 units into xs [m][pos][k] (ds_write_b16, 2B stride)
__device__ __forceinline__ void stage8(unsigned short* __restrict__ xs, int t,
                                       const f32x4u* va, const f32x4u* vb,
                                       const float* vc) {
#pragma unroll
  for (int i = 0; i < 8; ++i) {
    const int u = t + (i << 9);
    const int pos = u >> 8;        // 0..15
    const int k = u & 255;
    unsigned short* base = xs + pos * XS_KS + k;
    unsigned p01 = cvt_pk_bf16(va[i][0], va[i][1]);
    unsigned p23 = cvt_pk_bf16(va[i][2], va[i][3]);
    unsigned p45 = cvt_pk_bf16(vb[i][0], vb[i][1]);
    unsigned p67 = cvt_pk_bf16(vb[i][2], vb[i][3]);
    base[0 * XS_MS] = (unsigned short)p01;
    base[1 * XS_MS] = (unsigned short)(p01 >> 16);
    base[2 * XS_MS] = (unsigned short)p23;
    base[3 * XS_MS] = (unsigned short)(p23 >> 16);
    base[4 * XS_MS] = (unsigned short)p45;
    base[5 * XS_MS] = (unsigned short)(p45 >> 16);
    base[6 * XS_MS] = (unsigned short)p67;
    base[7 * XS_MS] = (unsigned short)(p67 >> 16);
    base[8 * XS_MS] = f2bf(vc[i]);
  }
}

// ---- main: 512 blocks x 512 threads (8 waves), 2 blocks/CU, NT=4 tiles ----
__global__ __launch_bounds__(512, 4) void eqlin_main(
    const float* __restrict__ x, const unsigned short* __restrict__ wt,
    float* __restrict__ out) {
  extern __shared__ char smem[];
  unsigned short* xs = reinterpret_cast<unsigned short*>(smem);  // [9][16][264]

  const int t = threadIdx.x;
  const long long blk = blockIdx.x;
  const float* xbase = x + blk * ((long long)NT * TILE_FLOATS);

  const int w = t >> 6;
  const int l = t & 63;
  const int cr = l & 15;          // A row (=pos) / B col (=c in tile)
  const int kg = (l >> 4) << 3;   // k-chunk base 0/8/16/24
  const int c0 = w << 5;          // 32 channels per wave
  const unsigned short* wtB = wt + (c0 + cr) * 256 + kg;

  float* stgw = reinterpret_cast<float*>(smem) + w * (POSB * STG_ROW);
  const int posb = (l >> 4) << 2;

  f32x4u va[8], vb[8];
  float vc[8];

  // ---- prologue: load + stage tile 0 ----
  load8(xbase, t, va, vb, vc);
  stage8(xs, t, va, vb, vc);
  bar_nodrain();

#pragma unroll 1
  for (int it = 0; it < NT; ++it) {
    // ---- compute tile it from xs ----
    const unsigned short* xsA = xs + cr * XS_KS + kg;

    f32x4 accA[4][2];  // m = 0..3
#pragma unroll
    for (int m = 0; m < 4; ++m)
#pragma unroll
      for (int ct = 0; ct < 2; ++ct) accA[m][ct] = (f32x4){0.f, 0.f, 0.f, 0.f};

#pragma unroll 2
    for (int ks = 0; ks < 8; ++ks) {
      const int kk = ks << 5;
      s16x8 b00 = *reinterpret_cast<const s16x8*>(wtB + kk);
      s16x8 b01 = *reinterpret_cast<const s16x8*>(wtB + 4096 + kk);
      s16x8 b10 = *reinterpret_cast<const s16x8*>(wtB + 65536 + kk);
      s16x8 b11 = *reinterpret_cast<const s16x8*>(wtB + 65536 + 4096 + kk);
      {
        s16x8 a = *reinterpret_cast<const s16x8*>(xsA + kk);
        accA[0][0] = __builtin_amdgcn_mfma_f32_16x16x32_bf16(a, b00, accA[0][0], 0, 0, 0);
        accA[0][1] = __builtin_amdgcn_mfma_f32_16x16x32_bf16(a, b01, accA[0][1], 0, 0, 0);
      }
#pragma unroll
      for (int m = 1; m < 4; ++m) {
        s16x8 a = *reinterpret_cast<const s16x8*>(xsA + m * XS_MS + kk);
        accA[m][0] = __builtin_amdgcn_mfma_f32_16x16x32_bf16(a, b10, accA[m][0], 0, 0, 0);
        accA[m][1] = __builtin_amdgcn_mfma_f32_16x16x32_bf16(a, b11, accA[m][1], 0, 0, 0);
      }
    }

    f32x4 accB[5][2];  // m = 4..8 (irr2)
#pragma unroll
    for (int m = 0; m < 5; ++m)
#pragma unroll
      for (int ct = 0; ct < 2; ++ct) accB[m][ct] = (f32x4){0.f, 0.f, 0.f, 0.f};

#pragma unroll 2
    for (int ks = 0; ks < 8; ++ks) {
      const int kk = ks << 5;
      s16x8 b20 = *reinterpret_cast<const s16x8*>(wtB + 2 * 65536 + kk);
      s16x8 b21 = *reinterpret_cast<const s16x8*>(wtB + 2 * 65536 + 4096 + kk);
#pragma unroll
      for (int m = 0; m < 5; ++m) {
        s16x8 a = *reinterpret_cast<const s16x8*>(xsA + (m + 4) * XS_MS + kk);
        accB[m][0] = __builtin_amdgcn_mfma_f32_16x16x32_bf16(a, b20, accB[m][0], 0, 0, 0);
        accB[m][1] = __builtin_amdgcn_mfma_f32_16x16x32_bf16(a, b21, accB[m][1], 0, 0, 0);
      }
    }
    bar_nodrain();  // all waves done reading xs; it becomes out-stage scratch

    f32x4* o4 = reinterpret_cast<f32x4*>(out) + (blk * NT + it) * 9216 + w * 72;

    // ---- out-stage ct0 (scatter -> read -> nt store), wave-local sync ----
#pragma unroll
    for (int m = 0; m < 9; ++m)
#pragma unroll
      for (int j = 0; j < 4; ++j) {
        float v = (m < 4) ? accA[m][0][j] : accB[m - 4][0][j];
        stgw[(posb + j) * STG_ROW + cr * 9 + m] = v;
      }
    asm volatile("s_waitcnt lgkmcnt(0)" ::: "memory");
#pragma unroll
    for (int q = 0; q < 9; ++q) {
      const int e = l + (q << 6);
      const int pos = (int)((unsigned)e / 36u);
      const int rem = e - pos * 36;
      f32x4 v = *reinterpret_cast<const f32x4*>(stgw + pos * STG_ROW + (rem << 2));
      __builtin_nontemporal_store(v, &o4[pos * 576 + rem]);
    }
    asm volatile("s_waitcnt lgkmcnt(0)" ::: "memory");  // ct0 reads done

    // ---- scatter ct1 (after this, acc is fully dead) ----
#pragma unroll
    for (int m = 0; m < 9; ++m)
#pragma unroll
      for (int j = 0; j < 4; ++j) {
        float v = (m < 4) ? accA[m][1][j] : accB[m - 4][1][j];
        stgw[(posb + j) * STG_ROW + cr * 9 + m] = v;
      }
    asm volatile("s_waitcnt lgkmcnt(0)" ::: "memory");

    // ---- ISSUE next tile's loads: acc dead, regs reuse acc slots;
    //      fills overlap ct1 stores + barrier + stage-writes ----
    if (it + 1 < NT) load8(xbase + (long long)(it + 1) * TILE_FLOATS, t, va, vb, vc);

    // ---- read + nt store ct1 ----
#pragma unroll
    for (int q = 0; q < 9; ++q) {
      const int e = l + (q << 6);
      const int pos = (int)((unsigned)e / 36u);
      const int rem = e - pos * 36;
      f32x4 v = *reinterpret_cast<const f32x4*>(stgw + pos * STG_ROW + (rem << 2));
      __builtin_nontemporal_store(v, &o4[pos * 576 + 36 + rem]);
    }

    if (it + 1 < NT) {
      bar_nodrain();  // ALL waves' stgw reads done -> xs region writable
      stage8(xs, t, va, vb, vc);  // cvt waits loads (counted vmcnt expected)
      bar_nodrain();  // staging visible to all before next compute
    }
  }
}

extern "C" void kernel_launch(void* const* d_in, const int* in_sizes, int n_in,
                              void* d_out, int out_size, void* d_ws, size_t ws_size,
                              hipStream_t stream) {
  const float* x = (const float*)d_in[0];
  const float* w0 = (const float*)d_in[1];
  const float* w1 = (const float*)d_in[2];
  const float* w2 = (const float*)d_in[3];
  unsigned short* wt = (unsigned short*)d_ws;  // 3*256*256 bf16 = 384 KB
  float* out = (float*)d_out;

  prep_w<<<48, 256, 0, stream>>>(w0, w1, w2, wt);

  (void)hipFuncSetAttribute(reinterpret_cast<const void*>(eqlin_main),
                            hipFuncAttributeMaxDynamicSharedMemorySize, SMEM_BYTES);
  eqlin_main<<<512, 512, SMEM_BYTES, stream>>>(x, wt, out);
}

// Round 10
// 172.583 us; speedup vs baseline: 1.6531x; 1.6531x over previous
//
#include <hip/hip_runtime.h>

// EquivariantLinear: out[pos, c, m] = pw * sum_k x[pos, k, m] * W_{l(m)}[k, c]
// pos = 32768, C_IN = C_OUT = 256, FEAT = 9 (irreps 1,3,5), pw = 1/16.
// R12 = R8 (champion, 162.7 us) + LAUNCH-TIME PHASE STAGGER, nothing else.
// Theory: the 2 co-resident blocks/CU convoy (identical timing -> both stage
// together, both compute together) so HBM read duty ~50%. Odd blocks of the
// first cohort (blockIdx < 512) sleep ~10 us before staging; replacement
// blocks inherit the offset phase via backfill. Internals identical to R8:
// 36-B-unit coalesced loads, cvt_pk converts, b16 LDS scatter-stage, 2-pass
// MFMA, per-wave LDS out-stage, nt stores.

typedef float f32x4 __attribute__((ext_vector_type(4)));
typedef float f32x4u __attribute__((ext_vector_type(4), aligned(4)));
typedef short s16x8 __attribute__((ext_vector_type(8)));

#define POSB 16                      // positions per block
#define XS_KS 264                    // padded k-stride (elems)
#define XS_MS (POSB * XS_KS)         // 4224 elems per m-plane
#define SMEM_BYTES (9 * XS_MS * 2)   // 76032 B
#define STG_ROW 148                  // out-stage row stride (floats); row=144 used
// per-wave out-stage: 16*148*4 = 9472 B; 8 waves = 75776 <= 76032 (aliases xs)

__device__ __forceinline__ unsigned short f2bf(float f) {
  unsigned u = __float_as_uint(f);
  return (unsigned short)((u + 0x7FFFu + ((u >> 16) & 1u)) >> 16);
}

__device__ __forceinline__ unsigned cvt_pk_bf16(float lo, float hi) {
  unsigned r;
  asm("v_cvt_pk_bf16_f32 %0, %1, %2" : "=v"(r) : "v"(lo), "v"(hi));
  return r;
}

// ---- prep: W^T bf16 image in ws: wt[irr][c][k] = pw * w_irr[k][c] ----
__global__ void prep_w(const float* __restrict__ w0, const float* __restrict__ w1,
                       const float* __restrict__ w2, unsigned short* __restrict__ wt) {
  const int b = blockIdx.x;
  const int irr = b / 16;
  const int tile = b % 16;
  const int k0 = (tile >> 2) << 6;
  const int c0 = (tile & 3) << 6;
  const float* w = (irr == 0) ? w0 : ((irr == 1) ? w1 : w2);
  __shared__ float lt[64 * 65];
  const int t = threadIdx.x;
#pragma unroll
  for (int i = 0; i < 16; ++i) {
    int e = t + (i << 8);
    int kk = e >> 6, cc = e & 63;
    lt[cc * 65 + kk] = w[(k0 + kk) * 256 + (c0 + cc)];
  }
  __syncthreads();
#pragma unroll
  for (int i = 0; i < 16; ++i) {
    int e = t + (i << 8);
    int cc = e >> 6, kk = e & 63;
    wt[irr * 65536 + (c0 + cc) * 256 + (k0 + kk)] = f2bf(lt[cc * 65 + kk] * 0.0625f);
  }
}

// ---- main: 2048 blocks x 512 threads (8 waves), 2 blocks/CU ----
__global__ __launch_bounds__(512, 4) void eqlin_main(
    const float* __restrict__ x, const unsigned short* __restrict__ wt,
    float* __restrict__ out) {
  extern __shared__ char smem[];
  unsigned short* xs = reinterpret_cast<unsigned short*>(smem);  // [9][16][264] bf16

  const int t = threadIdx.x;
  const long long blk = blockIdx.x;
  const float* xb = x + blk * (POSB * 2304);

  // ---- phase stagger: odd blocks of the first resident cohort sleep ~10 us
  //      so the two co-resident blocks/CU run offset phases (reads of one
  //      overlap compute/stores of the other). Backfill inherits the offset.
  if ((blockIdx.x & 1) && blockIdx.x < 512) {
#pragma unroll
    for (int i = 0; i < 3; ++i) __builtin_amdgcn_s_sleep(127);  // ~3.4 us each
  }

  // ---- stage x -> LDS bf16 [m][pos][k]: 4096 36-B units, 8 per thread ----
  {
    f32x4u va[8], vb[8];
    float vc[8];
#pragma unroll
    for (int i = 0; i < 8; ++i) {
      const float* s = xb + (t + (i << 9)) * 9;
      va[i] = *reinterpret_cast<const f32x4u*>(s);
      vb[i] = *reinterpret_cast<const f32x4u*>(s + 4);
      vc[i] = s[8];
    }
#pragma unroll
    for (int i = 0; i < 8; ++i) {
      const int u = t + (i << 9);
      const int pos = u >> 8;        // 0..15
      const int k = u & 255;
      unsigned short* base = xs + pos * XS_KS + k;
      unsigned p01 = cvt_pk_bf16(va[i][0], va[i][1]);
      unsigned p23 = cvt_pk_bf16(va[i][2], va[i][3]);
      unsigned p45 = cvt_pk_bf16(vb[i][0], vb[i][1]);
      unsigned p67 = cvt_pk_bf16(vb[i][2], vb[i][3]);
      base[0 * XS_MS] = (unsigned short)p01;
      base[1 * XS_MS] = (unsigned short)(p01 >> 16);
      base[2 * XS_MS] = (unsigned short)p23;
      base[3 * XS_MS] = (unsigned short)(p23 >> 16);
      base[4 * XS_MS] = (unsigned short)p45;
      base[5 * XS_MS] = (unsigned short)(p45 >> 16);
      base[6 * XS_MS] = (unsigned short)p67;
      base[7 * XS_MS] = (unsigned short)(p67 >> 16);
      base[8 * XS_MS] = f2bf(vc[i]);
    }
  }
  __syncthreads();

  const int w = t >> 6;
  const int l = t & 63;
  const int cr = l & 15;          // A row (=pos) / B col (=c in tile)
  const int kg = (l >> 4) << 3;   // k-chunk base 0/8/16/24
  const int c0 = w << 5;          // 32 channels per wave

  const unsigned short* xsA = xs + cr * XS_KS + kg;
  const unsigned short* wtB = wt + (c0 + cr) * 256 + kg;

  f32x4 accA[4][2];  // m = 0..3
#pragma unroll
  for (int m = 0; m < 4; ++m)
#pragma unroll
    for (int ct = 0; ct < 2; ++ct) accA[m][ct] = (f32x4){0.f, 0.f, 0.f, 0.f};

  // pass 1: m 0..3 (irr0 for m0, irr1 for m1..3)
#pragma unroll 2
  for (int ks = 0; ks < 8; ++ks) {
    const int kk = ks << 5;
    s16x8 b00 = *reinterpret_cast<const s16x8*>(wtB + kk);
    s16x8 b01 = *reinterpret_cast<const s16x8*>(wtB + 4096 + kk);
    s16x8 b10 = *reinterpret_cast<const s16x8*>(wtB + 65536 + kk);
    s16x8 b11 = *reinterpret_cast<const s16x8*>(wtB + 65536 + 4096 + kk);
    {
      s16x8 a = *reinterpret_cast<const s16x8*>(xsA + kk);
      accA[0][0] = __builtin_amdgcn_mfma_f32_16x16x32_bf16(a, b00, accA[0][0], 0, 0, 0);
      accA[0][1] = __builtin_amdgcn_mfma_f32_16x16x32_bf16(a, b01, accA[0][1], 0, 0, 0);
    }
#pragma unroll
    for (int m = 1; m < 4; ++m) {
      s16x8 a = *reinterpret_cast<const s16x8*>(xsA + m * XS_MS + kk);
      accA[m][0] = __builtin_amdgcn_mfma_f32_16x16x32_bf16(a, b10, accA[m][0], 0, 0, 0);
      accA[m][1] = __builtin_amdgcn_mfma_f32_16x16x32_bf16(a, b11, accA[m][1], 0, 0, 0);
    }
  }

  f32x4 accB[5][2];  // m = 4..8 (irr2)
#pragma unroll
  for (int m = 0; m < 5; ++m)
#pragma unroll
    for (int ct = 0; ct < 2; ++ct) accB[m][ct] = (f32x4){0.f, 0.f, 0.f, 0.f};

  // pass 2: m 4..8
#pragma unroll 2
  for (int ks = 0; ks < 8; ++ks) {
    const int kk = ks << 5;
    s16x8 b20 = *reinterpret_cast<const s16x8*>(wtB + 2 * 65536 + kk);
    s16x8 b21 = *reinterpret_cast<const s16x8*>(wtB + 2 * 65536 + 4096 + kk);
#pragma unroll
    for (int m = 0; m < 5; ++m) {
      s16x8 a = *reinterpret_cast<const s16x8*>(xsA + (m + 4) * XS_MS + kk);
      accB[m][0] = __builtin_amdgcn_mfma_f32_16x16x32_bf16(a, b20, accB[m][0], 0, 0, 0);
      accB[m][1] = __builtin_amdgcn_mfma_f32_16x16x32_bf16(a, b21, accB[m][1], 0, 0, 0);
    }
  }
  __syncthreads();  // xs fully consumed by ALL waves; stage may alias it

  // ---- per-wave out-stage (9472 B slice of smem), wave-internal sync only ----
  float* stgw = reinterpret_cast<float*>(smem) + w * (POSB * STG_ROW);
  const int posb = (l >> 4) << 2;
  f32x4* o4 = reinterpret_cast<f32x4*>(out) + blk * 9216 + w * 72;

#pragma unroll
  for (int ct = 0; ct < 2; ++ct) {
    // scatter acc -> stgw[pos][cr*9 + m]  (fp32, ~2-way banks: free)
#pragma unroll
    for (int m = 0; m < 9; ++m) {
#pragma unroll
      for (int j = 0; j < 4; ++j) {
        float v = (m < 4) ? accA[m][ct][j] : accB[m - 4][ct][j];
        stgw[(posb + j) * STG_ROW + cr * 9 + m] = v;
      }
    }
    asm volatile("s_waitcnt lgkmcnt(0)" ::: "memory");
    // coalesced float4 NON-TEMPORAL store of this wave's 16c x 9m slice
#pragma unroll
    for (int q = 0; q < 9; ++q) {
      const int e = l + (q << 6);                 // 0..575 float4s
      const int pos = (int)((unsigned)e / 36u);
      const int rem = e - pos * 36;
      f32x4 v = *reinterpret_cast<const f32x4*>(stgw + pos * STG_ROW + (rem << 2));
      __builtin_nontemporal_store(v, &o4[pos * 576 + ct * 36 + rem]);
    }
    asm volatile("s_waitcnt lgkmcnt(0)" ::: "memory");  // drain reads before next ct writes
  }
}

extern "C" void kernel_launch(void* const* d_in, const int* in_sizes, int n_in,
                              void* d_out, int out_size, void* d_ws, size_t ws_size,
                              hipStream_t stream) {
  const float* x = (const float*)d_in[0];
  const float* w0 = (const float*)d_in[1];
  const float* w1 = (const float*)d_in[2];
  const float* w2 = (const float*)d_in[3];
  unsigned short* wt = (unsigned short*)d_ws;  // 3*256*256 bf16 = 384 KB
  float* out = (float*)d_out;

  prep_w<<<48, 256, 0, stream>>>(w0, w1, w2, wt);

  (void)hipFuncSetAttribute(reinterpret_cast<const void*>(eqlin_main),
                            hipFuncAttributeMaxDynamicSharedMemorySize, SMEM_BYTES);
  eqlin_main<<<2048, 512, SMEM_BYTES, stream>>>(x, wt, out);
}